// Round 4
// baseline (135.552 us; speedup 1.0000x reference)
//
#include <hip/hip_runtime.h>

#define GAT_B   8
#define GAT_N   1024
#define GAT_DIN 256
#define GAT_H   8
#define GAT_HD  32
#define GAT_LOG2E 1.4426950408889634f

typedef unsigned short gu16;
typedef unsigned int   gu32;
typedef unsigned long long gu64;
typedef __bf16 bf16x8 __attribute__((ext_vector_type(8)));
typedef __bf16 bf16x4 __attribute__((ext_vector_type(4)));
typedef float  f32x4v __attribute__((ext_vector_type(4)));

#if __has_builtin(__builtin_amdgcn_exp2f)
#define GAT_EXP2(x) __builtin_amdgcn_exp2f(x)
#else
#define GAT_EXP2(x) exp2f(x)
#endif

__device__ __forceinline__ float gb2f(gu16 u) { return __uint_as_float(((gu32)u) << 16); }

// Parallel input-dtype self-detection (wave 0, 128 words). bf16 N(0,1):
// exponent <= ~131 in every u16; fp32 mantissa halves hit >=140 w.h.p.
__device__ __forceinline__ void gat_detect(const gu16* p, int t, int* sflag) {
    if (t < 64) {
        int e0 = (p[2 * t]     >> 7) & 0xFF;
        int e1 = (p[2 * t + 1] >> 7) & 0xFF;
        unsigned long long m = __ballot((e0 >= 140) || (e1 >= 140));
        if (t == 0) *sflag = (m != 0ULL);
    }
}

// ---------------------------------------------------------------------------
// K0: (a) adjacency int32 -> bitmask via wave ballot: pk[row][s] u64 covers
//     j = s*64..s*64+63 of row (bit = j&63; dword jc = j>>5, bit-in-dword
//     j&31 = 8g+e -- exactly the attn fragment order).
//     8192 rows / 256 blocks = 32 rows/block, 4 rows/wave, coalesced.
// (b) blocks 0..7: W[h] -> global bf16 fragment table wfg[h][8192] with
//     element (i,k) at (((i>>5)*32+k)*4+((i>>3)&3))*8+(i&7).
// ---------------------------------------------------------------------------
__global__ __launch_bounds__(512) void CustomGATLayer_90348932038855_pack(
    const void* __restrict__ Xv, const int* __restrict__ adj, const void* __restrict__ Wv,
    gu64* __restrict__ pk, __bf16* __restrict__ wfg)
{
    __shared__ int sflag;
    const int t = threadIdx.x, bid = blockIdx.x;
    gat_detect((const gu16*)Xv, t, &sflag);
    __syncthreads();
    const int fp32 = sflag;

    if (bid < 8) {                       // W fragment table (L2-resident, 128 KB)
        const int h = bid;
        if (fp32) {
            const float* ws = (const float*)Wv + (size_t)h * 8192;
            #pragma unroll
            for (int q = 0; q < 4; ++q) {
                int idx = q * 2048 + t * 4;
                int i = idx >> 5, k = idx & 31;
                float4 v = *(const float4*)(ws + idx);
                int d = h * 8192 + (((i >> 5) * 32 + k) * 4 + ((i >> 3) & 3)) * 8 + (i & 7);
                wfg[d] = (__bf16)v.x; wfg[d + 32] = (__bf16)v.y;
                wfg[d + 64] = (__bf16)v.z; wfg[d + 96] = (__bf16)v.w;
            }
        } else {
            const gu16* ws = (const gu16*)Wv + (size_t)h * 8192;
            gu16* wo = (gu16*)wfg;
            #pragma unroll
            for (int q = 0; q < 4; ++q) {
                int idx = q * 2048 + t * 4;
                int i = idx >> 5, k = idx & 31;
                ushort4 v = *(const ushort4*)(ws + idx);
                int d = h * 8192 + (((i >> 5) * 32 + k) * 4 + ((i >> 3) & 3)) * 8 + (i & 7);
                wo[d] = v.x; wo[d + 32] = v.y; wo[d + 64] = v.z; wo[d + 96] = v.w;
            }
        }
    }

    const int w = t >> 6, l = t & 63;
    const int r0 = bid * 32 + w * 4;
    for (int r = 0; r < 4; ++r) {
        const int* ar = adj + (size_t)(r0 + r) * GAT_N;
        gu64* po = pk + (size_t)(r0 + r) * 16;
        #pragma unroll
        for (int s = 0; s < 16; ++s) {
            int v = ar[s * 64 + l];
            gu64 m = __ballot(v != 0);
            if (l == 0) po[s] = m;
        }
    }
}

// ---------------------------------------------------------------------------
// K1: Wh = X @ W (all heads). Block = one 16-row tile x 8 head-waves, X tile
// staged ONCE in LDS (read-once: 8 MB total, vs 64 MB in the old per-head
// scheme -- that re-read was the hidden ~85 us). B-fragments from wfg (L2).
// whb written in bf16 B-fragment layout WhbF[b][h][jc][kg][col][e];
// e1/e2 pre-scaled by log2e. grid = 512 blocks x 512 thr.
// ---------------------------------------------------------------------------
__global__ __launch_bounds__(512) void CustomGATLayer_90348932038855_kernel(
    const void* __restrict__ Xv, const __bf16* __restrict__ wfg, const void* __restrict__ Av,
    __bf16* __restrict__ whb, float* __restrict__ e1, float* __restrict__ e2)
{
    __shared__ __align__(16) __bf16 Xl[16][264];   // padded row: 8-way worst on one-shot reads
    __shared__ int sflag;

    const int t = threadIdx.x;
    gat_detect((const gu16*)Xv, t, &sflag);

    const int bt = blockIdx.x;             // 0..511
    const int M0 = bt * 16, b = M0 >> 10, nloc = M0 & 1023;
    const int srow = t >> 5, scol = (t & 31) * 8;
    __syncthreads();
    const int fp32 = sflag;

    if (fp32) {
        const float* xs = (const float*)Xv + ((size_t)(b * GAT_N + nloc + srow)) * GAT_DIN + scol;
        float4 x0 = *(const float4*)(xs);
        float4 x1 = *(const float4*)(xs + 4);
        bf16x8 xv;
        xv[0] = (__bf16)x0.x; xv[1] = (__bf16)x0.y; xv[2] = (__bf16)x0.z; xv[3] = (__bf16)x0.w;
        xv[4] = (__bf16)x1.x; xv[5] = (__bf16)x1.y; xv[6] = (__bf16)x1.z; xv[7] = (__bf16)x1.w;
        *(bf16x8*)&Xl[srow][scol] = xv;
    } else {
        const gu16* xs = (const gu16*)Xv + ((size_t)(b * GAT_N + nloc + srow)) * GAT_DIN + scol;
        *(bf16x8*)&Xl[srow][scol] = *(const bf16x8*)xs;
    }
    __syncthreads();

    const int h = t >> 6, l = t & 63, g = l >> 4, c = l & 15;
    const __bf16* wf = wfg + h * 8192;

    f32x4v acc0 = {0.f, 0.f, 0.f, 0.f};
    f32x4v acc1 = {0.f, 0.f, 0.f, 0.f};
    #pragma unroll
    for (int kc = 0; kc < 8; ++kc) {
        bf16x8 af = *(const bf16x8*)&Xl[c][kc * 32 + 8 * g];
        bf16x8 b0 = *(const bf16x8*)(wf + ((kc * 32 + c) * 4 + g) * 8);
        bf16x8 b1 = *(const bf16x8*)(wf + ((kc * 32 + c + 16) * 4 + g) * 8);
        acc0 = __builtin_amdgcn_mfma_f32_16x16x32_bf16(af, b0, acc0, 0, 0, 0);
        acc1 = __builtin_amdgcn_mfma_f32_16x16x32_bf16(af, b1, acc1, 0, 0, 0);
    }

    // D layout: row = 4*g + q, col = c (HW-verified). Store Whb fragments.
    const int nb = nloc + 4 * g;
    const int jcc = nb >> 5, kg = (nb >> 3) & 3, e0 = nb & 7;
    const size_t fb = (((size_t)(b * GAT_H + h) * 32 + jcc) * 4 + kg) * 32;
    bf16x4 v0, v1;
    v0[0] = (__bf16)acc0[0]; v0[1] = (__bf16)acc0[1];
    v0[2] = (__bf16)acc0[2]; v0[3] = (__bf16)acc0[3];
    v1[0] = (__bf16)acc1[0]; v1[1] = (__bf16)acc1[1];
    v1[2] = (__bf16)acc1[2]; v1[3] = (__bf16)acc1[3];
    *(bf16x4*)(whb + (fb + c) * 8 + e0)      = v0;
    *(bf16x4*)(whb + (fb + c + 16) * 8 + e0) = v1;

    // e1/e2 (pre-scaled by log2e): reduce over col lanes (bits 0..3).
    float a1c, a1c16, a2c, a2c16;
    if (fp32) {
        const float* ap = (const float*)Av + h * 2 * GAT_HD;
        a1c = ap[c] * GAT_LOG2E;      a1c16 = ap[c + 16] * GAT_LOG2E;
        a2c = ap[32 + c] * GAT_LOG2E; a2c16 = ap[48 + c] * GAT_LOG2E;
    } else {
        const gu16* ap = (const gu16*)Av + h * 2 * GAT_HD;
        a1c = gb2f(ap[c]) * GAT_LOG2E;      a1c16 = gb2f(ap[c + 16]) * GAT_LOG2E;
        a2c = gb2f(ap[32 + c]) * GAT_LOG2E; a2c16 = gb2f(ap[48 + c]) * GAT_LOG2E;
    }
    float p1[4], p2[4];
    #pragma unroll
    for (int q = 0; q < 4; ++q) {
        p1[q] = acc0[q] * a1c + acc1[q] * a1c16;
        p2[q] = acc0[q] * a2c + acc1[q] * a2c16;
        #pragma unroll
        for (int mm = 1; mm <= 8; mm <<= 1) {
            p1[q] += __shfl_xor(p1[q], mm);
            p2[q] += __shfl_xor(p2[q], mm);
        }
    }
    if (c == 0) {
        const size_t eb = (size_t)(b * GAT_H + h) * GAT_N + nb;
        #pragma unroll
        for (int q = 0; q < 4; ++q) { e1[eb + q] = p1[q]; e2[eb + q] = p2[q]; }
    }
}

// ---------------------------------------------------------------------------
// K2 (attn): wave = one head x 16 query rows, full j sweep. Adjacency from
// LDS-staged packed bitmask (one broadcast ds_read_b32 + bit tests per jc --
// no adjacency global loads in the hot loop). Row-sums via 3rd MFMA against
// ones. Whb 2-deep prefetch (L2, XCD-pinned via b = id&7).
// ---------------------------------------------------------------------------
__global__ __launch_bounds__(512) void CustomGATLayer_90348932038855_attn(
    const void* __restrict__ Xv, const gu32* __restrict__ pk32, const void* __restrict__ biasv,
    const __bf16* __restrict__ whb, const float* __restrict__ e1f, const float* __restrict__ e2f,
    float* __restrict__ out)
{
    __shared__ __align__(16) float e2l[GAT_H * GAT_N];   // 32 KB
    __shared__ gu32 pkl[16][33];                          // padded: conflict-free
    __shared__ int sflag;

    const int t = threadIdx.x;
    const int h = t >> 6, l = t & 63, g = l >> 4, c = l & 15;
    const int id = blockIdx.x;
    const int b = id & 7, tile = id >> 3;
    const int i0 = tile * 16;

    gat_detect((const gu16*)Xv, t, &sflag);

    // Stage packed adjacency rows i0..i0+15 (2 KB).
    {
        const int prow = t >> 5, pjc = t & 31;
        pkl[prow][pjc] = pk32[((size_t)(b * GAT_N + i0 + prow)) * 32 + pjc];
    }
    // Stage this head's e2 row (4 KB, pre-scaled by log2e) into LDS.
    {
        const float* s = e2f + (size_t)(b * GAT_H + h) * GAT_N;
        float* d = e2l + h * GAT_N;
        #pragma unroll
        for (int q = 0; q < 4; ++q) {
            int off = (q * 64 + l) * 4;
            *(float4*)(d + off) = *(const float4*)(s + off);
        }
    }
    __syncthreads();
    const int fp32 = sflag;

    const float e1r = e1f[(size_t)(b * GAT_H + h) * GAT_N + i0 + c];
    const __bf16* whr = whb + (size_t)(b * GAT_H + h) * (GAT_N * GAT_HD) + g * 256 + c * 8;
    const float* e2h = e2l + h * GAT_N + 8 * g;

    // Whb prefetch 2-deep (L2-resident).
    bf16x8 wA0 = *(const bf16x8*)(whr),        wA1 = *(const bf16x8*)(whr + 128);
    bf16x8 wB0 = *(const bf16x8*)(whr + 1024), wB1 = *(const bf16x8*)(whr + 1152);

    f32x4v acc0 = {0.f, 0.f, 0.f, 0.f};
    f32x4v acc1 = {0.f, 0.f, 0.f, 0.f};
    f32x4v accS = {0.f, 0.f, 0.f, 0.f};
    bf16x8 onesf;
    #pragma unroll
    for (int e = 0; e < 8; ++e) onesf[e] = (__bf16)1.0f;

#define GAT_WCOMP(EV, IDX) {                        \
        float s_ = e1r + (EV);                      \
        s_ = fmaxf(s_, 0.2f * s_);                  \
        s_ = fminf(s_, 86.0f);                      \
        float w_ = GAT_EXP2(s_);                    \
        w_ = (ab & (1u << IDX)) ? w_ : 0.0f;        \
        pf[IDX] = (__bf16)w_; }

    #pragma unroll 2
    for (int jc = 0; jc < 32; ++jc) {
        const bf16x8 w0 = wA0, w1 = wA1;
        wA0 = wB0; wA1 = wB1;
        if (jc < 30) {
            const __bf16* wn = whr + (jc + 2) * 1024;
            wB0 = *(const bf16x8*)wn; wB1 = *(const bf16x8*)(wn + 128);
        }
        const gu32 ab = (pkl[c][jc] >> (8 * g)) & 0xFFu;   // bits e=0..7 for this lane
        float4 ea = *(const float4*)(e2h + jc * 32);
        float4 eb = *(const float4*)(e2h + jc * 32 + 4);
        bf16x8 pf;
        GAT_WCOMP(ea.x, 0) GAT_WCOMP(ea.y, 1)
        GAT_WCOMP(ea.z, 2) GAT_WCOMP(ea.w, 3)
        GAT_WCOMP(eb.x, 4) GAT_WCOMP(eb.y, 5)
        GAT_WCOMP(eb.z, 6) GAT_WCOMP(eb.w, 7)
        acc0 = __builtin_amdgcn_mfma_f32_16x16x32_bf16(pf, w0, acc0, 0, 0, 0);
        acc1 = __builtin_amdgcn_mfma_f32_16x16x32_bf16(pf, w1, acc1, 0, 0, 0);
        accS = __builtin_amdgcn_mfma_f32_16x16x32_bf16(pf, onesf, accS, 0, 0, 0);
    }
#undef GAT_WCOMP

    float bv0, bv1;
    if (fp32) {
        const float* bp = (const float*)biasv + h * GAT_HD;
        bv0 = bp[c]; bv1 = bp[c + 16];
    } else {
        const gu16* bp = (const gu16*)biasv + h * GAT_HD;
        bv0 = gb2f(bp[c]); bv1 = gb2f(bp[c + 16]);
    }

    // accS[q] holds the row-sum for row 4g+q in EVERY column -> no shuffles.
    float* ob = out + (size_t)(b * GAT_N + i0) * (GAT_H * GAT_HD) + h * GAT_HD + c;
    #pragma unroll
    for (int q = 0; q < 4; ++q) {
        float d = accS[q];
        float r = (d > 0.f) ? (1.0f / d) : 0.0f;
        float o0 = fmaxf(acc0[q] * r + bv0, 0.f);
        float o1 = fmaxf(acc1[q] * r + bv1, 0.f);
        ob[(size_t)(4 * g + q) * (GAT_H * GAT_HD)]      = o0;
        ob[(size_t)(4 * g + q) * (GAT_H * GAT_HD) + 16] = o1;
    }
}

extern "C" void kernel_launch(void* const* d_in, const int* in_sizes, int n_in,
                              void* d_out, int out_size, void* d_ws, size_t ws_size,
                              hipStream_t stream) {
    const void* X    = d_in[0];              // node_features [8][1024][256]
    const int*  adj  = (const int*)d_in[1];  // adjacency int32 [8][1024][1024]
    const void* Wm   = d_in[2];              // W [8][256][32]
    const void* Av   = d_in[3];              // a [8][64]
    const void* bias = d_in[4];              // bias [256]
    float* outp = (float*)d_out;             // fp32 output (reference dtype)

    __bf16* whb = (__bf16*)d_ws;                                   // 4 MB
    float* e1  = (float*)(whb + (size_t)GAT_B * GAT_H * GAT_N * GAT_HD);
    float* e2  = e1 + (size_t)GAT_B * GAT_H * GAT_N;
    __bf16* wfg = (__bf16*)(e2 + (size_t)GAT_B * GAT_H * GAT_N);   // 128 KB
    gu64* pk   = (gu64*)(wfg + (size_t)GAT_H * GAT_DIN * GAT_HD);  // 1 MB

    CustomGATLayer_90348932038855_pack
        <<<dim3(256), 512, 0, stream>>>(X, adj, Wm, pk, wfg);
    CustomGATLayer_90348932038855_kernel
        <<<dim3(512), 512, 0, stream>>>(X, wfg, Av, whb, e1, e2);
    CustomGATLayer_90348932038855_attn
        <<<dim3((GAT_N / 16) * GAT_B), 512, 0, stream>>>(
            X, (const gu32*)pk, bias, whb, e1, e2, outp);
}

// Round 5
// 121.242 us; speedup vs baseline: 1.1180x; 1.1180x over previous
//
#include <hip/hip_runtime.h>

#define GAT_B   8
#define GAT_N   1024
#define GAT_DIN 256
#define GAT_H   8
#define GAT_HD  32
#define GAT_LOG2E 1.4426950408889634f

typedef unsigned short gu16;
typedef unsigned int   gu32;
typedef __bf16 bf16x8 __attribute__((ext_vector_type(8)));
typedef __bf16 bf16x4 __attribute__((ext_vector_type(4)));
typedef float  f32x4v __attribute__((ext_vector_type(4)));

#if __has_builtin(__builtin_amdgcn_exp2f)
#define GAT_EXP2(x) __builtin_amdgcn_exp2f(x)
#else
#define GAT_EXP2(x) exp2f(x)
#endif

__device__ __forceinline__ float gb2f(gu16 u) { return __uint_as_float(((gu32)u) << 16); }

// Parallel input-dtype self-detection (wave 0, 128 words). bf16 N(0,1):
// exponent <= ~131 in every u16; fp32 mantissa halves hit >=140 w.h.p.
__device__ __forceinline__ void gat_detect(const gu16* p, int t, int* sflag) {
    if (t < 64) {
        int e0 = (p[2 * t]     >> 7) & 0xFF;
        int e1 = (p[2 * t + 1] >> 7) & 0xFF;
        unsigned long long m = __ballot((e0 >= 140) || (e1 >= 140));
        if (t == 0) *sflag = (m != 0ULL);
    }
}

// ---------------------------------------------------------------------------
// K0: W -> global bf16 fragment table wfg[h][8192], element (i,k) at
// (((i>>5)*32+k)*4+((i>>3)&3))*8+(i&7). grid = 8 blocks (one per head).
// (Adjacency packing moved INTO attn -- its rows coincide with attn's tile.)
// ---------------------------------------------------------------------------
__global__ __launch_bounds__(512) void CustomGATLayer_90348932038855_pack(
    const void* __restrict__ Xv, const void* __restrict__ Wv, __bf16* __restrict__ wfg)
{
    __shared__ int sflag;
    const int t = threadIdx.x, h = blockIdx.x;
    gat_detect((const gu16*)Xv, t, &sflag);
    __syncthreads();
    const int fp32 = sflag;

    if (fp32) {
        const float* ws = (const float*)Wv + (size_t)h * 8192;
        #pragma unroll
        for (int q = 0; q < 4; ++q) {
            int idx = q * 2048 + t * 4;
            int i = idx >> 5, k = idx & 31;
            float4 v = *(const float4*)(ws + idx);
            int d = h * 8192 + (((i >> 5) * 32 + k) * 4 + ((i >> 3) & 3)) * 8 + (i & 7);
            wfg[d] = (__bf16)v.x; wfg[d + 32] = (__bf16)v.y;
            wfg[d + 64] = (__bf16)v.z; wfg[d + 96] = (__bf16)v.w;
        }
    } else {
        const gu16* ws = (const gu16*)Wv + (size_t)h * 8192;
        gu16* wo = (gu16*)wfg;
        #pragma unroll
        for (int q = 0; q < 4; ++q) {
            int idx = q * 2048 + t * 4;
            int i = idx >> 5, k = idx & 31;
            ushort4 v = *(const ushort4*)(ws + idx);
            int d = h * 8192 + (((i >> 5) * 32 + k) * 4 + ((i >> 3) & 3)) * 8 + (i & 7);
            wo[d] = v.x; wo[d + 32] = v.y; wo[d + 64] = v.z; wo[d + 96] = v.w;
        }
    }
}

// ---------------------------------------------------------------------------
// K1: Wh = X @ W (all heads). Block = one 16-row tile x 8 head-waves, X tile
// staged ONCE in LDS (read-once: 8 MB total). B-fragments from wfg (L2).
// whb written in bf16 B-fragment layout WhbF[b][h][jc][kg][col][e];
// e1/e2 pre-scaled by log2e. grid = 512 blocks x 512 thr.
// ---------------------------------------------------------------------------
__global__ __launch_bounds__(512) void CustomGATLayer_90348932038855_kernel(
    const void* __restrict__ Xv, const __bf16* __restrict__ wfg, const void* __restrict__ Av,
    __bf16* __restrict__ whb, float* __restrict__ e1, float* __restrict__ e2)
{
    __shared__ __align__(16) __bf16 Xl[16][264];   // 528-B row stride = 33x16B: 2-way max
    __shared__ int sflag;

    const int t = threadIdx.x;
    gat_detect((const gu16*)Xv, t, &sflag);

    const int bt = blockIdx.x;             // 0..511
    const int M0 = bt * 16, b = M0 >> 10, nloc = M0 & 1023;
    const int srow = t >> 5, scol = (t & 31) * 8;
    __syncthreads();
    const int fp32 = sflag;

    if (fp32) {
        const float* xs = (const float*)Xv + ((size_t)(b * GAT_N + nloc + srow)) * GAT_DIN + scol;
        float4 x0 = *(const float4*)(xs);
        float4 x1 = *(const float4*)(xs + 4);
        bf16x8 xv;
        xv[0] = (__bf16)x0.x; xv[1] = (__bf16)x0.y; xv[2] = (__bf16)x0.z; xv[3] = (__bf16)x0.w;
        xv[4] = (__bf16)x1.x; xv[5] = (__bf16)x1.y; xv[6] = (__bf16)x1.z; xv[7] = (__bf16)x1.w;
        *(bf16x8*)&Xl[srow][scol] = xv;
    } else {
        const gu16* xs = (const gu16*)Xv + ((size_t)(b * GAT_N + nloc + srow)) * GAT_DIN + scol;
        *(bf16x8*)&Xl[srow][scol] = *(const bf16x8*)xs;
    }
    __syncthreads();

    const int h = t >> 6, l = t & 63, g = l >> 4, c = l & 15;
    const __bf16* wf = wfg + h * 8192;

    f32x4v acc0 = {0.f, 0.f, 0.f, 0.f};
    f32x4v acc1 = {0.f, 0.f, 0.f, 0.f};
    #pragma unroll
    for (int kc = 0; kc < 8; ++kc) {
        bf16x8 af = *(const bf16x8*)&Xl[c][kc * 32 + 8 * g];
        bf16x8 b0 = *(const bf16x8*)(wf + ((kc * 32 + c) * 4 + g) * 8);
        bf16x8 b1 = *(const bf16x8*)(wf + ((kc * 32 + c + 16) * 4 + g) * 8);
        acc0 = __builtin_amdgcn_mfma_f32_16x16x32_bf16(af, b0, acc0, 0, 0, 0);
        acc1 = __builtin_amdgcn_mfma_f32_16x16x32_bf16(af, b1, acc1, 0, 0, 0);
    }

    // D layout: row = 4*g + q, col = c (HW-verified). Store Whb fragments.
    const int nb = nloc + 4 * g;
    const int jcc = nb >> 5, kg = (nb >> 3) & 3, e0 = nb & 7;
    const size_t fb = (((size_t)(b * GAT_H + h) * 32 + jcc) * 4 + kg) * 32;
    bf16x4 v0, v1;
    v0[0] = (__bf16)acc0[0]; v0[1] = (__bf16)acc0[1];
    v0[2] = (__bf16)acc0[2]; v0[3] = (__bf16)acc0[3];
    v1[0] = (__bf16)acc1[0]; v1[1] = (__bf16)acc1[1];
    v1[2] = (__bf16)acc1[2]; v1[3] = (__bf16)acc1[3];
    *(bf16x4*)(whb + (fb + c) * 8 + e0)      = v0;
    *(bf16x4*)(whb + (fb + c + 16) * 8 + e0) = v1;

    // e1/e2 (pre-scaled by log2e): reduce over col lanes (bits 0..3).
    float a1c, a1c16, a2c, a2c16;
    if (fp32) {
        const float* ap = (const float*)Av + h * 2 * GAT_HD;
        a1c = ap[c] * GAT_LOG2E;      a1c16 = ap[c + 16] * GAT_LOG2E;
        a2c = ap[32 + c] * GAT_LOG2E; a2c16 = ap[48 + c] * GAT_LOG2E;
    } else {
        const gu16* ap = (const gu16*)Av + h * 2 * GAT_HD;
        a1c = gb2f(ap[c]) * GAT_LOG2E;      a1c16 = gb2f(ap[c + 16]) * GAT_LOG2E;
        a2c = gb2f(ap[32 + c]) * GAT_LOG2E; a2c16 = gb2f(ap[48 + c]) * GAT_LOG2E;
    }
    float p1[4], p2[4];
    #pragma unroll
    for (int q = 0; q < 4; ++q) {
        p1[q] = acc0[q] * a1c + acc1[q] * a1c16;
        p2[q] = acc0[q] * a2c + acc1[q] * a2c16;
        #pragma unroll
        for (int mm = 1; mm <= 8; mm <<= 1) {
            p1[q] += __shfl_xor(p1[q], mm);
            p2[q] += __shfl_xor(p2[q], mm);
        }
    }
    if (c == 0) {
        const size_t eb = (size_t)(b * GAT_H + h) * GAT_N + nb;
        #pragma unroll
        for (int q = 0; q < 4; ++q) { e1[eb + q] = p1[q]; e2[eb + q] = p2[q]; }
    }
}

// ---------------------------------------------------------------------------
// K2 (attn): wave = one head x 16 query rows, full j sweep. Adjacency packed
// IN-BLOCK from raw int32 (thread t: row t>>5, dword t&31, 8 int4 loads ->
// 32 bits) -- each adjacency row read exactly once grid-wide, no separate
// pack kernel. Row-sums via 3rd MFMA against ones. 4-deep whb prefetch (L2,
// XCD-pinned via b = id&7).
// ---------------------------------------------------------------------------
__global__ __launch_bounds__(512) void CustomGATLayer_90348932038855_attn(
    const void* __restrict__ Xv, const int* __restrict__ adj, const void* __restrict__ biasv,
    const __bf16* __restrict__ whb, const float* __restrict__ e1f, const float* __restrict__ e2f,
    float* __restrict__ out)
{
    __shared__ __align__(16) float e2l[GAT_H * GAT_N];   // 32 KB
    __shared__ gu32 pkl[16][33];                          // padded: conflict-free
    __shared__ int sflag;

    const int t = threadIdx.x;
    const int h = t >> 6, l = t & 63, g = l >> 4, c = l & 15;
    const int id = blockIdx.x;
    const int b = id & 7, tile = id >> 3;
    const int i0 = tile * 16;

    gat_detect((const gu16*)Xv, t, &sflag);

    // In-block adjacency pack: bit p of pkl[row][d] = adj[b][i0+row][d*32+p].
    {
        const int prow = t >> 5, pd = t & 31;
        const int* ar = adj + ((size_t)(b * GAT_N + i0 + prow)) * GAT_N + pd * 32;
        gu32 m = 0;
        #pragma unroll
        for (int q = 0; q < 8; ++q) {
            int4 v = *(const int4*)(ar + q * 4);
            m |= (v.x != 0 ? 1u : 0u) << (q * 4);
            m |= (v.y != 0 ? 1u : 0u) << (q * 4 + 1);
            m |= (v.z != 0 ? 1u : 0u) << (q * 4 + 2);
            m |= (v.w != 0 ? 1u : 0u) << (q * 4 + 3);
        }
        pkl[prow][pd] = m;
    }
    // Stage this head's e2 row (4 KB, pre-scaled by log2e) into LDS.
    {
        const float* s = e2f + (size_t)(b * GAT_H + h) * GAT_N;
        float* d = e2l + h * GAT_N;
        #pragma unroll
        for (int q = 0; q < 4; ++q) {
            int off = (q * 64 + l) * 4;
            *(float4*)(d + off) = *(const float4*)(s + off);
        }
    }
    __syncthreads();
    const int fp32 = sflag;

    const float e1r = e1f[(size_t)(b * GAT_H + h) * GAT_N + i0 + c];
    const __bf16* whr = whb + (size_t)(b * GAT_H + h) * (GAT_N * GAT_HD) + g * 256 + c * 8;
    const float* e2h = e2l + h * GAT_N + 8 * g;

    // whb prefetch 4-deep (L2-resident, ~300 cyc): 8 b128 loads in flight.
    bf16x8 wA0 = *(const bf16x8*)(whr),        wA1 = *(const bf16x8*)(whr + 128);
    bf16x8 wB0 = *(const bf16x8*)(whr + 1024), wB1 = *(const bf16x8*)(whr + 1152);
    bf16x8 wC0 = *(const bf16x8*)(whr + 2048), wC1 = *(const bf16x8*)(whr + 2176);
    bf16x8 wD0 = *(const bf16x8*)(whr + 3072), wD1 = *(const bf16x8*)(whr + 3200);

    f32x4v acc0 = {0.f, 0.f, 0.f, 0.f};
    f32x4v acc1 = {0.f, 0.f, 0.f, 0.f};
    f32x4v accS = {0.f, 0.f, 0.f, 0.f};
    bf16x8 onesf;
    #pragma unroll
    for (int e = 0; e < 8; ++e) onesf[e] = (__bf16)1.0f;

    float bv0, bv1;
    if (fp32) {
        const float* bp = (const float*)biasv + h * GAT_HD;
        bv0 = bp[c]; bv1 = bp[c + 16];
    } else {
        const gu16* bp = (const gu16*)biasv + h * GAT_HD;
        bv0 = gb2f(bp[c]); bv1 = gb2f(bp[c + 16]);
    }

#define GAT_WCOMP(EV, IDX) {                        \
        float s_ = e1r + (EV);                      \
        s_ = fmaxf(s_, 0.2f * s_);                  \
        s_ = fminf(s_, 86.0f);                      \
        float w_ = GAT_EXP2(s_);                    \
        w_ = (ab & (1u << IDX)) ? w_ : 0.0f;        \
        pf[IDX] = (__bf16)w_; }

    #pragma unroll 4
    for (int jc = 0; jc < 32; ++jc) {
        const bf16x8 w0 = wA0, w1 = wA1;
        wA0 = wB0; wA1 = wB1; wB0 = wC0; wB1 = wC1; wC0 = wD0; wC1 = wD1;
        if (jc < 28) {
            const __bf16* wn = whr + (jc + 4) * 1024;
            wD0 = *(const bf16x8*)wn; wD1 = *(const bf16x8*)(wn + 128);
        }
        const gu32 ab = (pkl[c][jc] >> (8 * g)) & 0xFFu;   // bits e=0..7 for this lane
        float4 ea = *(const float4*)(e2h + jc * 32);
        float4 eb = *(const float4*)(e2h + jc * 32 + 4);
        bf16x8 pf;
        GAT_WCOMP(ea.x, 0) GAT_WCOMP(ea.y, 1)
        GAT_WCOMP(ea.z, 2) GAT_WCOMP(ea.w, 3)
        GAT_WCOMP(eb.x, 4) GAT_WCOMP(eb.y, 5)
        GAT_WCOMP(eb.z, 6) GAT_WCOMP(eb.w, 7)
        acc0 = __builtin_amdgcn_mfma_f32_16x16x32_bf16(pf, w0, acc0, 0, 0, 0);
        acc1 = __builtin_amdgcn_mfma_f32_16x16x32_bf16(pf, w1, acc1, 0, 0, 0);
        accS = __builtin_amdgcn_mfma_f32_16x16x32_bf16(pf, onesf, accS, 0, 0, 0);
    }
#undef GAT_WCOMP

    // accS[q] holds the row-sum for row 4g+q in EVERY column -> no shuffles.
    float* ob = out + (size_t)(b * GAT_N + i0) * (GAT_H * GAT_HD) + h * GAT_HD + c;
    #pragma unroll
    for (int q = 0; q < 4; ++q) {
        float d = accS[q];
        float r = (d > 0.f) ? (1.0f / d) : 0.0f;
        float o0 = fmaxf(acc0[q] * r + bv0, 0.f);
        float o1 = fmaxf(acc1[q] * r + bv1, 0.f);
        ob[(size_t)(4 * g + q) * (GAT_H * GAT_HD)]      = o0;
        ob[(size_t)(4 * g + q) * (GAT_H * GAT_HD) + 16] = o1;
    }
}

extern "C" void kernel_launch(void* const* d_in, const int* in_sizes, int n_in,
                              void* d_out, int out_size, void* d_ws, size_t ws_size,
                              hipStream_t stream) {
    const void* X    = d_in[0];              // node_features [8][1024][256]
    const int*  adj  = (const int*)d_in[1];  // adjacency int32 [8][1024][1024]
    const void* Wm   = d_in[2];              // W [8][256][32]
    const void* Av   = d_in[3];              // a [8][64]
    const void* bias = d_in[4];              // bias [256]
    float* outp = (float*)d_out;             // fp32 output (reference dtype)

    __bf16* whb = (__bf16*)d_ws;                                   // 4 MB
    float* e1  = (float*)(whb + (size_t)GAT_B * GAT_H * GAT_N * GAT_HD);
    float* e2  = e1 + (size_t)GAT_B * GAT_H * GAT_N;
    __bf16* wfg = (__bf16*)(e2 + (size_t)GAT_B * GAT_H * GAT_N);   // 128 KB

    CustomGATLayer_90348932038855_pack
        <<<dim3(8), 512, 0, stream>>>(X, Wm, wfg);
    CustomGATLayer_90348932038855_kernel
        <<<dim3(512), 512, 0, stream>>>(X, wfg, Av, whb, e1, e2);
    CustomGATLayer_90348932038855_attn
        <<<dim3((GAT_N / 16) * GAT_B), 512, 0, stream>>>(
            X, adj, bias, whb, e1, e2, outp);
}